// Round 12
// baseline (117.063 us; speedup 1.0000x reference)
//
#include <hip/hip_runtime.h>

#define BATCH 8192
#define IN_DIM 512
#define NT 64
#define NI 31
#define NL 32
#define ODIM 16
#define NPAD (NT*NL)   // 2048 padded GEMM columns
#define NCB 16         // column blocks (2048/128)

typedef __attribute__((ext_vector_type(8))) short bf16x8;
typedef __attribute__((ext_vector_type(4))) float f32x4;

__device__ __forceinline__ unsigned short f2b(float f) {
  union { float f; unsigned int u; } v; v.f = f;
  unsigned int r = v.u + 0x7fffu + ((v.u >> 16) & 1u);   // RNE
  return (unsigned short)(r >> 16);
}
__device__ __forceinline__ float b2f(unsigned short h) {
  union { unsigned int u; float f; } v; v.u = ((unsigned int)h) << 16;
  return v.f;
}

// ---------------------------------------------------------------------------
// prep: emit A and B in MFMA FRAGMENT-MAJOR order so the GEMM needs no LDS:
//   layout granule index G = strip*1024 + w*64 + quad*16 + l15, 8 elems each,
//   holding  src[row = strip*16 + l15][k = w*32 + quad*8 .. +8].
//   A wave frag load = base + strip*8192 + w*512 + lane*8  (1 KB coalesced).
// W rows tree-padded to 32 (col 31 zero). lsm = leaf softmax * (1/NT).
// ---------------------------------------------------------------------------
__global__ __launch_bounds__(256) void prep_kernel(
    const float* __restrict__ x, const float* __restrict__ W,
    const float* __restrict__ leafs,
    unsigned short* __restrict__ xa, unsigned short* __restrict__ wb,
    float* __restrict__ lsm)
{
  const int NXg = BATCH*IN_DIM/8;   // 524288 granules
  const int NWg = NPAD*IN_DIM/8;    // 131072 granules
  const int NS  = NT*NL;            // 2048 leaf rows
  int gid = blockIdx.x*256 + threadIdx.x;
  if (gid < NXg) {
    int strip = gid >> 10, rem = gid & 1023;
    int w = rem >> 6, rem2 = rem & 63;
    int quad = rem2 >> 4, c = rem2 & 15;
    int m = strip*16 + c;
    const float4* s = (const float4*)(x + (size_t)m*IN_DIM + w*32 + quad*8);
    float4 v0 = s[0], v1 = s[1];
    ushort4 o0, o1;
    o0.x=f2b(v0.x); o0.y=f2b(v0.y); o0.z=f2b(v0.z); o0.w=f2b(v0.w);
    o1.x=f2b(v1.x); o1.y=f2b(v1.y); o1.z=f2b(v1.z); o1.w=f2b(v1.w);
    ((ushort4*)xa)[gid*2]   = o0;
    ((ushort4*)xa)[gid*2+1] = o1;
  } else if ((gid -= NXg) < NWg) {
    int strip = gid >> 10, rem = gid & 1023;
    int w = rem >> 6, rem2 = rem & 63;
    int quad = rem2 >> 4, c = rem2 & 15;
    int n = strip*16 + c;
    int t = n >> 5, i = n & 31;
    ushort4 o0, o1;
    if (i == 31) { o0.x=o0.y=o0.z=o0.w=0; o1=o0; }
    else {
      const float4* s = (const float4*)(W + (size_t)(t*NI+i)*IN_DIM + w*32 + quad*8);
      float4 v0 = s[0], v1 = s[1];
      o0.x=f2b(v0.x); o0.y=f2b(v0.y); o0.z=f2b(v0.z); o0.w=f2b(v0.w);
      o1.x=f2b(v1.x); o1.y=f2b(v1.y); o1.z=f2b(v1.z); o1.w=f2b(v1.w);
    }
    ((ushort4*)wb)[gid*2]   = o0;
    ((ushort4*)wb)[gid*2+1] = o1;
  } else if ((gid -= NWg) < NS) {
    const float* src = leafs + (size_t)gid*ODIM;
    float m = src[0];
    #pragma unroll
    for (int o=1;o<ODIM;++o) m = fmaxf(m, src[o]);
    float e[ODIM]; float s = 0.f;
    #pragma unroll
    for (int o=0;o<ODIM;++o) { e[o] = __expf(src[o]-m); s += e[o]; }
    float inv = 1.f/(s*(float)NT);
    #pragma unroll
    for (int o=0;o<ODIM;++o) lsm[(size_t)gid*ODIM+o] = e[o]*inv;
  }
}

// ---------------------------------------------------------------------------
// fused: bf16 GEMM (M=8192,N=2048,K=512) tile 128x128, NO LDS / NO BARRIERS
// in the K-loop: fragment-major operands stream straight from global (L2-hot
// via XCD swizzle: A-strip 1 MB + B 2 MB per XCD). 4 waves (2x2 of 64x64),
// 16 windows x (8 coalesced 1KB loads + 16 MFMAs). LDS used only by the
// epilogue: sigmoid -> Pt[128][130], route expansion -> Rt[128][136],
// second MFMA (routes[128x128] @ lsm_slice[128x16]). LDS 34816 B.
// ---------------------------------------------------------------------------
__global__ __launch_bounds__(256, 3) void fused_kernel(
    const unsigned short* __restrict__ xa, const unsigned short* __restrict__ wb,
    const float* __restrict__ bias, const float* __restrict__ lsm,
    float* __restrict__ part)
{
  // max(Pt 128*130=16640, Rt 128*136=17408) shorts
  __shared__ __align__(16) unsigned short smem[17408];   // 34816 B

  const int tid  = threadIdx.x;
  const int lane = tid & 63;
  const int wave = tid >> 6;
  const int wm = wave & 1, wn = wave >> 1;   // wave-tile: 64x64

  // XCD-aware block swizzle: xcd = bid&7 covers 8 m-strips x all n
  const int bid  = blockIdx.x;
  const int loc  = bid >> 3;                 // 0..127
  const int n_t  = loc & 15;                 // 0..15
  const int m_t  = (bid & 7)*8 + (loc >> 4); // 0..63
  const int m0 = m_t * 128, n0 = n_t * 128;

  f32x4 acc[4][4];
  #pragma unroll
  for (int i=0;i<4;++i)
    #pragma unroll
    for (int j=0;j<4;++j) { f32x4 z = {0.f,0.f,0.f,0.f}; acc[i][j] = z; }

  const int l15 = lane & 15, quad = lane >> 4;

  // fragment-major bases: strip = row/16; wave's A strips m_t*8 + wm*4 + mi,
  // B strips n_t*8 + wn*4 + ni; lane offset lane*8 = (quad*16+l15)*8.
  const unsigned short* pA = xa + ((size_t)(m_t*8 + wm*4))*8192 + lane*8;
  const unsigned short* pB = wb + ((size_t)(n_t*8 + wn*4))*8192 + lane*8;

  #pragma unroll
  for (int w = 0; w < 16; ++w) {
    bf16x8 af[4], bfr[4];
    #pragma unroll
    for (int mi=0;mi<4;++mi)
      af[mi]  = *(const bf16x8*)(pA + mi*8192 + w*512);
    #pragma unroll
    for (int ni=0;ni<4;++ni)
      bfr[ni] = *(const bf16x8*)(pB + ni*8192 + w*512);
    #pragma unroll
    for (int mi=0;mi<4;++mi)
      #pragma unroll
      for (int ni=0;ni<4;++ni)
        acc[mi][ni] = __builtin_amdgcn_mfma_f32_16x16x32_bf16(
            af[mi], bfr[ni], acc[mi][ni], 0, 0, 0);
  }

  // lsm B-frags for the second MFMA: lane(l15=n, quad) elem j = bf16 of
  // lsm[(t0+s)*32 + quad*8 + j][l15]
  bf16x8 bleaf[4];
  {
    const int t0 = n_t * 4;
    #pragma unroll
    for (int s=0;s<4;++s) {
      union { bf16x8 v; unsigned short u[8]; } tmp;
      #pragma unroll
      for (int j=0;j<8;++j)
        tmp.u[j] = f2b(lsm[((size_t)(t0+s)*NL + quad*8 + j)*ODIM + l15]);
      bleaf[s] = tmp.v;
    }
  }

  // Phase A: bias + sigmoid -> Pt[128][130] bf16 (first LDS touch, no barrier
  // needed before it)
  unsigned short* Pt = smem;
  #pragma unroll
  for (int ni=0;ni<4;++ni) {
    int cl = wn*64 + ni*16 + l15;          // local col 0..127
    int gcol = n0 + cl;
    int tt = gcol >> 5, ii = gcol & 31;
    float bv = (ii < NI) ? bias[tt*NI + ii] : 0.f;
    #pragma unroll
    for (int mi=0;mi<4;++mi) {
      int lrow = wm*64 + mi*16 + quad*4;
      #pragma unroll
      for (int r=0;r<4;++r) {
        float v = acc[mi][ni][r] + bv;
        Pt[(lrow + r)*130 + cl] = f2b(1.f/(1.f + __expf(-v)));
      }
    }
  }
  __syncthreads();

  // Phase B: thread pair (row = tid>>1) expands 2 trees each into bf16 route
  // pairs; streamed per tree to keep VGPR pressure low.
  const int row  = tid >> 1;
  const int half = tid & 1;
  unsigned int rt[32];
  #pragma unroll
  for (int sel=0; sel<2; ++sel) {
    const int tl = half*2 + sel;
    const unsigned short* pr = Pt + row*130 + tl*32;
    float v[32];
    float p0 = b2f(pr[0]);
    v[0] = p0; v[1] = 1.f - p0;
    #pragma unroll
    for (int d=1; d<=4; ++d) {
      const int s = 1 << d;
      #pragma unroll
      for (int j=s-1; j>=0; --j) {
        float pj = b2f(pr[(s-1)+j]);
        float base = v[j];
        v[2*j]   = base * pj;
        v[2*j+1] = base * (1.f - pj);
      }
    }
    #pragma unroll
    for (int k=0;k<16;++k)
      rt[sel*16+k] = (unsigned int)f2b(v[2*k]) | ((unsigned int)f2b(v[2*k+1]) << 16);
  }
  __syncthreads();   // all Pt reads done before Rt overwrites

  // Rt[128][136] bf16 rows (272 B, 16B-aligned); thread writes its 2 trees
  unsigned int* Rt32 = (unsigned int*)smem;
  {
    uint4* dst = (uint4*)(Rt32 + row*68 + half*32);
    #pragma unroll
    for (int c=0;c<8;++c) {
      uint4 w; w.x=rt[c*4]; w.y=rt[c*4+1]; w.z=rt[c*4+2]; w.w=rt[c*4+3];
      dst[c] = w;
    }
  }
  __syncthreads();

  // second MFMA: routes[128x128] @ lsm[128x16]; wave covers mtiles 2w..2w+1
  const unsigned short* RtS = smem;
  #pragma unroll
  for (int mt=0; mt<2; ++mt) {
    const int mrow = (wave*2 + mt)*16;
    f32x4 a2 = {0.f,0.f,0.f,0.f};
    #pragma unroll
    for (int s=0;s<4;++s) {
      bf16x8 af2 = *(const bf16x8*)(RtS + (mrow + l15)*136 + s*32 + quad*8);
      a2 = __builtin_amdgcn_mfma_f32_16x16x32_bf16(af2, bleaf[s], a2, 0, 0, 0);
    }
    // C/D: col=l15 (ODIM), row=quad*4+r
    float* op = part + ((size_t)n_t*BATCH + (m0 + mrow + quad*4))*ODIM + l15;
    #pragma unroll
    for (int r=0;r<4;++r)
      op[r*ODIM] = a2[r];
  }
}

// ---------------------------------------------------------------------------
// reduce: out[row][o] = sum over 16 colblock partials
// ---------------------------------------------------------------------------
__global__ __launch_bounds__(256) void reduce_kernel(
    const float* __restrict__ part, float* __restrict__ out)
{
  int gid = blockIdx.x*256 + threadIdx.x;   // 32768 float4 tasks
  const float4* p4 = (const float4*)part;
  float4 s = p4[gid];
  #pragma unroll
  for (int cb=1; cb<NCB; ++cb) {
    float4 v = p4[(size_t)cb*(BATCH*ODIM/4) + gid];
    s.x+=v.x; s.y+=v.y; s.z+=v.z; s.w+=v.w;
  }
  ((float4*)out)[gid] = s;
}

// ---------------------------------------------------------------------------
extern "C" void kernel_launch(void* const* d_in, const int* in_sizes, int n_in,
                              void* d_out, int out_size, void* d_ws, size_t ws_size,
                              hipStream_t stream) {
  const float* x     = (const float*)d_in[0];
  const float* W     = (const float*)d_in[1];
  const float* b     = (const float*)d_in[2];
  const float* leafs = (const float*)d_in[3];
  float* out = (float*)d_out;

  char* ws = (char*)d_ws;
  unsigned short* xa  = (unsigned short*)ws;                       // 8,388,608 B
  unsigned short* wb  = (unsigned short*)(ws + 8388608);           // 2,097,152 B
  float*          lsm = (float*)(ws + 10485760);                   //   131,072 B
  float*          part= (float*)(ws + 10616832);                   // 8,388,608 B

  const int total = BATCH*(IN_DIM/8) + NPAD*(IN_DIM/8) + NT*NL;    // 657408
  prep_kernel<<<dim3((total + 255)/256), dim3(256), 0, stream>>>(
      x, W, leafs, xa, wb, lsm);
  fused_kernel<<<dim3(1024), dim3(256), 0, stream>>>(
      xa, wb, b, lsm, part);
  reduce_kernel<<<dim3(BATCH*ODIM/4/256), dim3(256), 0, stream>>>(part, out);
}

// Round 13
// 115.869 us; speedup vs baseline: 1.0103x; 1.0103x over previous
//
#include <hip/hip_runtime.h>

#define BATCH 8192
#define IN_DIM 512
#define NT 64
#define NI 31
#define NL 32
#define ODIM 16
#define NPAD (NT*NL)   // 2048 padded GEMM columns
#define NCB 16         // column blocks (2048/128)

typedef __attribute__((ext_vector_type(8))) short bf16x8;
typedef __attribute__((ext_vector_type(4))) float f32x4;

__device__ __forceinline__ unsigned short f2b(float f) {
  union { float f; unsigned int u; } v; v.f = f;
  unsigned int r = v.u + 0x7fffu + ((v.u >> 16) & 1u);   // RNE
  return (unsigned short)(r >> 16);
}
__device__ __forceinline__ float b2f(unsigned short h) {
  union { unsigned int u; float f; } v; v.u = ((unsigned int)h) << 16;
  return v.f;
}

// ---------------------------------------------------------------------------
// prep: emit A and B in MFMA FRAGMENT-MAJOR order so the GEMM needs no LDS:
//   granule G = strip*1024 + w*64 + quad*16 + l15 (8 elems) holds
//   src[row = strip*16 + l15][k = w*32 + quad*8 .. +8].
// W rows tree-padded to 32 (col 31 zero). lsm = leaf softmax * (1/NT).
// ---------------------------------------------------------------------------
__global__ __launch_bounds__(256) void prep_kernel(
    const float* __restrict__ x, const float* __restrict__ W,
    const float* __restrict__ leafs,
    unsigned short* __restrict__ xa, unsigned short* __restrict__ wb,
    float* __restrict__ lsm)
{
  const int NXg = BATCH*IN_DIM/8;   // 524288 granules
  const int NWg = NPAD*IN_DIM/8;    // 131072 granules
  const int NS  = NT*NL;            // 2048 leaf rows
  int gid = blockIdx.x*256 + threadIdx.x;
  if (gid < NXg) {
    int strip = gid >> 10, rem = gid & 1023;
    int w = rem >> 6, rem2 = rem & 63;
    int quad = rem2 >> 4, c = rem2 & 15;
    int m = strip*16 + c;
    const float4* s = (const float4*)(x + (size_t)m*IN_DIM + w*32 + quad*8);
    float4 v0 = s[0], v1 = s[1];
    ushort4 o0, o1;
    o0.x=f2b(v0.x); o0.y=f2b(v0.y); o0.z=f2b(v0.z); o0.w=f2b(v0.w);
    o1.x=f2b(v1.x); o1.y=f2b(v1.y); o1.z=f2b(v1.z); o1.w=f2b(v1.w);
    ((ushort4*)xa)[gid*2]   = o0;
    ((ushort4*)xa)[gid*2+1] = o1;
  } else if ((gid -= NXg) < NWg) {
    int strip = gid >> 10, rem = gid & 1023;
    int w = rem >> 6, rem2 = rem & 63;
    int quad = rem2 >> 4, c = rem2 & 15;
    int n = strip*16 + c;
    int t = n >> 5, i = n & 31;
    ushort4 o0, o1;
    if (i == 31) { o0.x=o0.y=o0.z=o0.w=0; o1=o0; }
    else {
      const float4* s = (const float4*)(W + (size_t)(t*NI+i)*IN_DIM + w*32 + quad*8);
      float4 v0 = s[0], v1 = s[1];
      o0.x=f2b(v0.x); o0.y=f2b(v0.y); o0.z=f2b(v0.z); o0.w=f2b(v0.w);
      o1.x=f2b(v1.x); o1.y=f2b(v1.y); o1.z=f2b(v1.z); o1.w=f2b(v1.w);
    }
    ((ushort4*)wb)[gid*2]   = o0;
    ((ushort4*)wb)[gid*2+1] = o1;
  } else if ((gid -= NWg) < NS) {
    const float* src = leafs + (size_t)gid*ODIM;
    float m = src[0];
    #pragma unroll
    for (int o=1;o<ODIM;++o) m = fmaxf(m, src[o]);
    float e[ODIM]; float s = 0.f;
    #pragma unroll
    for (int o=0;o<ODIM;++o) { e[o] = __expf(src[o]-m); s += e[o]; }
    float inv = 1.f/(s*(float)NT);
    #pragma unroll
    for (int o=0;o<ODIM;++o) lsm[(size_t)gid*ODIM+o] = e[o]*inv;
  }
}

// ---------------------------------------------------------------------------
// fused: bf16 GEMM (M=8192,N=2048,K=512) tile 128x128, no LDS / no barriers
// in the K-loop; fragment-major operands stream from global (L2-hot, XCD
// swizzle). R13: EXPLICIT 2-WINDOW SOFTWARE PIPELINE (prefetch w+1 while
// computing w, ping-pong register sets) + __launch_bounds__(256,2) so the
// register budget (256 unified) holds both windows -> 2x outstanding loads.
// Epilogue: sigmoid -> Pt[128][130], route expansion -> Rt[128][136],
// second MFMA (routes[128x128] @ lsm_slice[128x16]). LDS 34816 B.
// ---------------------------------------------------------------------------
__global__ __launch_bounds__(256, 2) void fused_kernel(
    const unsigned short* __restrict__ xa, const unsigned short* __restrict__ wb,
    const float* __restrict__ bias, const float* __restrict__ lsm,
    float* __restrict__ part)
{
  // max(Pt 128*130=16640, Rt 128*136=17408) shorts
  __shared__ __align__(16) unsigned short smem[17408];   // 34816 B

  const int tid  = threadIdx.x;
  const int lane = tid & 63;
  const int wave = tid >> 6;
  const int wm = wave & 1, wn = wave >> 1;   // wave-tile: 64x64

  // XCD-aware block swizzle: xcd = bid&7 covers 8 m-strips x all n
  const int bid  = blockIdx.x;
  const int loc  = bid >> 3;                 // 0..127
  const int n_t  = loc & 15;                 // 0..15
  const int m_t  = (bid & 7)*8 + (loc >> 4); // 0..63
  const int m0 = m_t * 128, n0 = n_t * 128;

  f32x4 acc[4][4];
  #pragma unroll
  for (int i=0;i<4;++i)
    #pragma unroll
    for (int j=0;j<4;++j) { f32x4 z = {0.f,0.f,0.f,0.f}; acc[i][j] = z; }

  const int l15 = lane & 15, quad = lane >> 4;

  // fragment-major bases: wave's A strips m_t*8 + wm*4 + mi, B strips
  // n_t*8 + wn*4 + ni; lane offset lane*8.
  const unsigned short* pA = xa + ((size_t)(m_t*8 + wm*4))*8192 + lane*8;
  const unsigned short* pB = wb + ((size_t)(n_t*8 + wn*4))*8192 + lane*8;

  bf16x8 af0[4], bf0[4], af1[4], bf1[4];
  #pragma unroll
  for (int mi=0;mi<4;++mi) af0[mi] = *(const bf16x8*)(pA + mi*8192);
  #pragma unroll
  for (int ni=0;ni<4;++ni) bf0[ni] = *(const bf16x8*)(pB + ni*8192);

  #pragma unroll
  for (int w = 0; w < 16; w += 2) {
    // prefetch window w+1 into set1 (always valid: w<=14)
    #pragma unroll
    for (int mi=0;mi<4;++mi) af1[mi] = *(const bf16x8*)(pA + mi*8192 + (w+1)*512);
    #pragma unroll
    for (int ni=0;ni<4;++ni) bf1[ni] = *(const bf16x8*)(pB + ni*8192 + (w+1)*512);
    // compute window w on set0
    #pragma unroll
    for (int mi=0;mi<4;++mi)
      #pragma unroll
      for (int ni=0;ni<4;++ni)
        acc[mi][ni] = __builtin_amdgcn_mfma_f32_16x16x32_bf16(
            af0[mi], bf0[ni], acc[mi][ni], 0, 0, 0);
    // prefetch window w+2 into set0
    if (w + 2 < 16) {
      #pragma unroll
      for (int mi=0;mi<4;++mi) af0[mi] = *(const bf16x8*)(pA + mi*8192 + (w+2)*512);
      #pragma unroll
      for (int ni=0;ni<4;++ni) bf0[ni] = *(const bf16x8*)(pB + ni*8192 + (w+2)*512);
    }
    // compute window w+1 on set1
    #pragma unroll
    for (int mi=0;mi<4;++mi)
      #pragma unroll
      for (int ni=0;ni<4;++ni)
        acc[mi][ni] = __builtin_amdgcn_mfma_f32_16x16x32_bf16(
            af1[mi], bf1[ni], acc[mi][ni], 0, 0, 0);
  }

  // lsm B-frags for the second MFMA: lane(l15=n, quad) elem j = bf16 of
  // lsm[(t0+s)*32 + quad*8 + j][l15]
  bf16x8 bleaf[4];
  {
    const int t0 = n_t * 4;
    #pragma unroll
    for (int s=0;s<4;++s) {
      union { bf16x8 v; unsigned short u[8]; } tmp;
      #pragma unroll
      for (int j=0;j<8;++j)
        tmp.u[j] = f2b(lsm[((size_t)(t0+s)*NL + quad*8 + j)*ODIM + l15]);
      bleaf[s] = tmp.v;
    }
  }

  // Phase A: bias + sigmoid -> Pt[128][130] bf16
  unsigned short* Pt = smem;
  #pragma unroll
  for (int ni=0;ni<4;++ni) {
    int cl = wn*64 + ni*16 + l15;          // local col 0..127
    int gcol = n0 + cl;
    int tt = gcol >> 5, ii = gcol & 31;
    float bv = (ii < NI) ? bias[tt*NI + ii] : 0.f;
    #pragma unroll
    for (int mi=0;mi<4;++mi) {
      int lrow = wm*64 + mi*16 + quad*4;
      #pragma unroll
      for (int r=0;r<4;++r) {
        float v = acc[mi][ni][r] + bv;
        Pt[(lrow + r)*130 + cl] = f2b(1.f/(1.f + __expf(-v)));
      }
    }
  }
  __syncthreads();

  // Phase B: thread pair (row = tid>>1) expands 2 trees each into bf16 route
  // pairs; streamed per tree to keep VGPR pressure low.
  const int row  = tid >> 1;
  const int half = tid & 1;
  unsigned int rt[32];
  #pragma unroll
  for (int sel=0; sel<2; ++sel) {
    const int tl = half*2 + sel;
    const unsigned short* pr = Pt + row*130 + tl*32;
    float v[32];
    float p0 = b2f(pr[0]);
    v[0] = p0; v[1] = 1.f - p0;
    #pragma unroll
    for (int d=1; d<=4; ++d) {
      const int s = 1 << d;
      #pragma unroll
      for (int j=s-1; j>=0; --j) {
        float pj = b2f(pr[(s-1)+j]);
        float base = v[j];
        v[2*j]   = base * pj;
        v[2*j+1] = base * (1.f - pj);
      }
    }
    #pragma unroll
    for (int k=0;k<16;++k)
      rt[sel*16+k] = (unsigned int)f2b(v[2*k]) | ((unsigned int)f2b(v[2*k+1]) << 16);
  }
  __syncthreads();   // all Pt reads done before Rt overwrites

  // Rt[128][136] bf16 rows (272 B, 16B-aligned); thread writes its 2 trees
  unsigned int* Rt32 = (unsigned int*)smem;
  {
    uint4* dst = (uint4*)(Rt32 + row*68 + half*32);
    #pragma unroll
    for (int c=0;c<8;++c) {
      uint4 w; w.x=rt[c*4]; w.y=rt[c*4+1]; w.z=rt[c*4+2]; w.w=rt[c*4+3];
      dst[c] = w;
    }
  }
  __syncthreads();

  // second MFMA: routes[128x128] @ lsm[128x16]; wave covers mtiles 2w..2w+1
  const unsigned short* RtS = smem;
  #pragma unroll
  for (int mt=0; mt<2; ++mt) {
    const int mrow = (wave*2 + mt)*16;
    f32x4 a2 = {0.f,0.f,0.f,0.f};
    #pragma unroll
    for (int s=0;s<4;++s) {
      bf16x8 af2 = *(const bf16x8*)(RtS + (mrow + l15)*136 + s*32 + quad*8);
      a2 = __builtin_amdgcn_mfma_f32_16x16x32_bf16(af2, bleaf[s], a2, 0, 0, 0);
    }
    // C/D: col=l15 (ODIM), row=quad*4+r
    float* op = part + ((size_t)n_t*BATCH + (m0 + mrow + quad*4))*ODIM + l15;
    #pragma unroll
    for (int r=0;r<4;++r)
      op[r*ODIM] = a2[r];
  }
}

// ---------------------------------------------------------------------------
// reduce: out[row][o] = sum over 16 colblock partials
// ---------------------------------------------------------------------------
__global__ __launch_bounds__(256) void reduce_kernel(
    const float* __restrict__ part, float* __restrict__ out)
{
  int gid = blockIdx.x*256 + threadIdx.x;   // 32768 float4 tasks
  const float4* p4 = (const float4*)part;
  float4 s = p4[gid];
  #pragma unroll
  for (int cb=1; cb<NCB; ++cb) {
    float4 v = p4[(size_t)cb*(BATCH*ODIM/4) + gid];
    s.x+=v.x; s.y+=v.y; s.z+=v.z; s.w+=v.w;
  }
  ((float4*)out)[gid] = s;
}

// ---------------------------------------------------------------------------
extern "C" void kernel_launch(void* const* d_in, const int* in_sizes, int n_in,
                              void* d_out, int out_size, void* d_ws, size_t ws_size,
                              hipStream_t stream) {
  const float* x     = (const float*)d_in[0];
  const float* W     = (const float*)d_in[1];
  const float* b     = (const float*)d_in[2];
  const float* leafs = (const float*)d_in[3];
  float* out = (float*)d_out;

  char* ws = (char*)d_ws;
  unsigned short* xa  = (unsigned short*)ws;                       // 8,388,608 B
  unsigned short* wb  = (unsigned short*)(ws + 8388608);           // 2,097,152 B
  float*          lsm = (float*)(ws + 10485760);                   //   131,072 B
  float*          part= (float*)(ws + 10616832);                   // 8,388,608 B

  const int total = BATCH*(IN_DIM/8) + NPAD*(IN_DIM/8) + NT*NL;    // 657408
  prep_kernel<<<dim3((total + 255)/256), dim3(256), 0, stream>>>(
      x, W, leafs, xa, wb, lsm);
  fused_kernel<<<dim3(1024), dim3(256), 0, stream>>>(
      xa, wb, b, lsm, part);
  reduce_kernel<<<dim3(BATCH*ODIM/4/256), dim3(256), 0, stream>>>(part, out);
}